// Round 1
// baseline (1329.728 us; speedup 1.0000x reference)
//
#include <hip/hip_runtime.h>
#include <hip/hip_bf16.h>

typedef __hip_bfloat16 bf16;
typedef __attribute__((ext_vector_type(8))) short bf16x8;
typedef __attribute__((ext_vector_type(4))) float f32x4;

#define BIG_NEG -1000000000.0f

static constexpr int B_  = 256;
static constexpr int H_  = 512;
static constexpr int SX_ = 34;
static constexpr int SY_ = 34;
static constexpr int IND = 66;   // IN_DIM
static constexpr int OP_ = 80;   // padded OUT_DIM (65 -> 80)

__device__ __forceinline__ f32x4 mfma16(bf16x8 a, bf16x8 b, f32x4 c) {
  return __builtin_amdgcn_mfma_f32_16x16x32_bf16(a, b, c, 0, 0, 0);
}
__device__ __forceinline__ bf16x8 ldfrag(const bf16* p) {
  return *reinterpret_cast<const bf16x8*>(p);
}
__device__ __forceinline__ float sigm(float x)  { return 1.0f / (1.0f + __expf(-x)); }
__device__ __forceinline__ float tanhx(float x) { return 2.0f * sigm(2.0f * x) - 1.0f; }

// ---------------------------------------------------------------------------
// prep kernels
// ---------------------------------------------------------------------------
__global__ void decode_tokens(const float* __restrict__ src,
                              const float* __restrict__ tgt,
                              int* __restrict__ tok_x, int* __restrict__ tok_y) {
  int idx = blockIdx.x * 256 + threadIdx.x;
  const int half = SX_ * B_;
  if (idx >= 2 * half) return;
  const float* base = (idx < half) ? src : tgt;
  int* outp         = (idx < half) ? tok_x : tok_y;
  int k = (idx < half) ? idx : idx - half;
  const float* p = base + (size_t)k * IND;
  int tok = -1;
  for (int v = 0; v < IND; ++v) if (p[v] > 0.5f) tok = v;
  outp[k] = tok;
}

__global__ void convert_bf16_kernel(const float* __restrict__ in,
                                    bf16* __restrict__ out, int n) {
  int i = blockIdx.x * blockDim.x + threadIdx.x;
  int stride = gridDim.x * blockDim.x;
  for (; i < n; i += stride) out[i] = __float2bfloat16(in[i]);
}

__global__ void pad_head_w(const float* __restrict__ Wsub, const float* __restrict__ Wins,
                           bf16* __restrict__ outs, bf16* __restrict__ outi) {
  int idx = blockIdx.x * 256 + threadIdx.x;  // over 80*1024
  if (idx >= OP_ * 1024) return;
  int r = idx >> 10;
  int c = idx & 1023;
  float vs = (r < 65) ? Wsub[r * 1024 + c] : 0.0f;
  float vi = (r < 65) ? Wins[r * 1024 + c] : 0.0f;
  outs[idx] = __float2bfloat16(vs);
  outi[idx] = __float2bfloat16(vi);
}

// ---------------------------------------------------------------------------
// LSTM step: one launch per timestep. grid = 256 wgs x 256 thr.
//   blocks [0,64)   : fwd LSTM  (H=512,  32 k-slices x 2 batch halves)
//   blocks [64,128) : rev LSTM  (H=512)
//   blocks [128,256): modern    (H=1024, 64 k-slices x 2 batch halves)
// Each wave: 32 batch rows x 16 hidden units x all 4 gates; no LDS, no sync.
// ---------------------------------------------------------------------------
template <int HH>
__device__ __forceinline__ void lstm_step_body(
    int tokpos, const int* __restrict__ tokarr,
    const float* __restrict__ Wih, const float* __restrict__ bias,
    const bf16* __restrict__ Whh, float* __restrict__ cbuf,
    const bf16* __restrict__ hrd, bf16* __restrict__ hwr,
    int kslice, int bhalf) {
  const int lane = threadIdx.x & 63;
  const int wave = threadIdx.x >> 6;
  const int lo = lane & 15, quad = lane >> 4;
  const int b0 = bhalf * 128 + wave * 32;
  const int k0 = kslice * 16;

  f32x4 acc[2][4];
#pragma unroll
  for (int mt = 0; mt < 2; ++mt)
#pragma unroll
    for (int g = 0; g < 4; ++g) acc[mt][g] = (f32x4){0.f, 0.f, 0.f, 0.f};

  const bf16* Arow0 = hrd + (size_t)(b0 + lo) * HH + quad * 8;
  const bf16* Arow1 = Arow0 + (size_t)16 * HH;
  const bf16* Brow[4];
#pragma unroll
  for (int g = 0; g < 4; ++g)
    Brow[g] = Whh + (size_t)(g * HH + k0 + lo) * HH + quad * 8;

  for (int kk = 0; kk < HH; kk += 32) {
    bf16x8 a0 = ldfrag(Arow0 + kk);
    bf16x8 a1 = ldfrag(Arow1 + kk);
    bf16x8 bb[4];
#pragma unroll
    for (int g = 0; g < 4; ++g) bb[g] = ldfrag(Brow[g] + kk);
#pragma unroll
    for (int g = 0; g < 4; ++g) {
      acc[0][g] = mfma16(a0, bb[g], acc[0][g]);
      acc[1][g] = mfma16(a1, bb[g], acc[1][g]);
    }
  }

  const int kg = k0 + lo;
  const int* tokp = tokarr + tokpos * B_;
#pragma unroll
  for (int mt = 0; mt < 2; ++mt) {
#pragma unroll
    for (int r = 0; r < 4; ++r) {
      int b = b0 + mt * 16 + quad * 4 + r;
      int tok = tokp[b];
      float g4[4];
#pragma unroll
      for (int g = 0; g < 4; ++g) {
        int n = g * HH + kg;
        float v = acc[mt][g][r] + bias[n];
        if (tok >= 0) v += Wih[(size_t)n * IND + tok];
        g4[g] = v;
      }
      size_t ci = (size_t)b * HH + kg;
      float co = cbuf[ci];
      float cn = sigm(g4[1]) * co + sigm(g4[0]) * tanhx(g4[2]);
      float h  = sigm(g4[3]) * tanhx(cn);
      cbuf[ci] = cn;
      hwr[ci] = __float2bfloat16(h);
    }
  }
}

__global__ __launch_bounds__(256) void lstm_step(
    int t, const int* __restrict__ tok_x, const int* __restrict__ tok_y,
    const float* Wih_f, const float* b_f, const bf16* Whh_f_b,
    const float* Wih_r, const float* b_r, const bf16* Whh_r_b,
    const float* Wih_m, const float* b_m, const bf16* Whh_m_b,
    float* c_f, float* c_r, float* c_m,
    bf16* fwd_all, bf16* rev_all, bf16* y_all) {
  int id = blockIdx.x;
  if (id < 64) {
    int kslice = id >> 1, bhalf = id & 1;
    lstm_step_body<512>(t, tok_x, Wih_f, b_f, Whh_f_b, c_f,
                        fwd_all + (size_t)t * B_ * 512,
                        fwd_all + (size_t)(t + 1) * B_ * 512, kslice, bhalf);
  } else if (id < 128) {
    int id2 = id - 64;
    int kslice = id2 >> 1, bhalf = id2 & 1;
    lstm_step_body<512>(33 - t, tok_x, Wih_r, b_r, Whh_r_b, c_r,
                        rev_all + (size_t)t * B_ * 512,
                        rev_all + (size_t)(t + 1) * B_ * 512, kslice, bhalf);
  } else {
    int id2 = id - 128;
    int kslice = id2 >> 1, bhalf = id2 & 1;
    lstm_step_body<1024>(t, tok_y, Wih_m, b_m, Whh_m_b, c_m,
                         y_all + (size_t)t * B_ * 1024,
                         y_all + (size_t)(t + 1) * B_ * 1024, kslice, bhalf);
  }
}

// ---------------------------------------------------------------------------
// head kernel: lx = x_emb @ W^T (no bias), ly = y_emb @ W^T + b, both heads.
// Output layout: [34][256][80] f32 each.
// grid 272: blocks [0,136) = x side, [136,272) = y side; wave = one m-tile (16
// rows of the flattened [34*256] M dim) x 5 n-tiles x 2 heads.
// ---------------------------------------------------------------------------
__global__ __launch_bounds__(256) void head_kernel(
    const bf16* __restrict__ fwd_all, const bf16* __restrict__ rev_all,
    const bf16* __restrict__ y_all,
    const bf16* __restrict__ Wsub_b, const bf16* __restrict__ Wins_b,
    const float* __restrict__ b_sub, const float* __restrict__ b_ins,
    float* __restrict__ lx_sub, float* __restrict__ lx_ins,
    float* __restrict__ ly_sub, float* __restrict__ ly_ins) {
  const int lane = threadIdx.x & 63, wave = threadIdx.x >> 6;
  const int lo = lane & 15, quad = lane >> 4;
  int blk = blockIdx.x;
  bool yside = (blk >= 136);
  int mb = yside ? blk - 136 : blk;
  int mtile = mb * 4 + wave;   // 0..543
  int m0 = mtile * 16;
  int ij = m0 >> 8;            // i or j (m-tile never crosses an i boundary)
  int bb = m0 & 255;

  f32x4 acc[2][5];
#pragma unroll
  for (int h2 = 0; h2 < 2; ++h2)
#pragma unroll
    for (int n5 = 0; n5 < 5; ++n5) acc[h2][n5] = (f32x4){0.f, 0.f, 0.f, 0.f};

  const bf16* wrow[2][5];
#pragma unroll
  for (int n5 = 0; n5 < 5; ++n5) {
    wrow[0][n5] = Wsub_b + (size_t)(n5 * 16 + lo) * 1024 + quad * 8;
    wrow[1][n5] = Wins_b + (size_t)(n5 * 16 + lo) * 1024 + quad * 8;
  }

  if (!yside) {
    const bf16* Af = fwd_all + ((size_t)(ij + 1) * B_ + bb + lo) * 512 + quad * 8;
    const bf16* Ar = rev_all + ((size_t)(34 - ij) * B_ + bb + lo) * 512 + quad * 8;
    for (int kk = 0; kk < 1024; kk += 32) {
      bf16x8 a = (kk < 512) ? ldfrag(Af + kk) : ldfrag(Ar + kk - 512);
#pragma unroll
      for (int h2 = 0; h2 < 2; ++h2)
#pragma unroll
        for (int n5 = 0; n5 < 5; ++n5)
          acc[h2][n5] = mfma16(a, ldfrag(wrow[h2][n5] + kk), acc[h2][n5]);
    }
  } else {
    const bf16* Ay = y_all + ((size_t)(ij + 1) * B_ + bb + lo) * 1024 + quad * 8;
    for (int kk = 0; kk < 1024; kk += 32) {
      bf16x8 a = ldfrag(Ay + kk);
#pragma unroll
      for (int h2 = 0; h2 < 2; ++h2)
#pragma unroll
        for (int n5 = 0; n5 < 5; ++n5)
          acc[h2][n5] = mfma16(a, ldfrag(wrow[h2][n5] + kk), acc[h2][n5]);
    }
  }

#pragma unroll
  for (int h2 = 0; h2 < 2; ++h2) {
    float* dst = yside ? (h2 ? ly_ins : ly_sub) : (h2 ? lx_ins : lx_sub);
#pragma unroll
    for (int n5 = 0; n5 < 5; ++n5) {
      int n = n5 * 16 + lo;
      float bias = 0.0f;
      if (yside && n < 65) bias = h2 ? b_ins[n] : b_sub[n];
#pragma unroll
      for (int r = 0; r < 4; ++r) {
        int b = bb + quad * 4 + r;
        dst[((size_t)ij * B_ + b) * OP_ + n] = acc[h2][n5][r] + bias;
      }
    }
  }
}

// ---------------------------------------------------------------------------
// pair kernel: per (i,j,b): logsumexp over 65 of lx[i,b,:]+ly[j,b,:] for both
// heads; assemble the 4 output channels with masks. grid 34*34, block 256 (=b)
// ---------------------------------------------------------------------------
__device__ __forceinline__ void head_lse(const float* __restrict__ px,
                                         const float* __restrict__ py, int sym,
                                         float& logZ, float& v64, float& vs) {
  float v[68];
  const float4* px4 = reinterpret_cast<const float4*>(px);
  const float4* py4 = reinterpret_cast<const float4*>(py);
#pragma unroll
  for (int q = 0; q < 17; ++q) {
    float4 xa = px4[q], yb = py4[q];
    v[4 * q + 0] = xa.x + yb.x;
    v[4 * q + 1] = xa.y + yb.y;
    v[4 * q + 2] = xa.z + yb.z;
    v[4 * q + 3] = xa.w + yb.w;
  }
  float m = v[0];
#pragma unroll
  for (int o = 1; o < 65; ++o) m = fmaxf(m, v[o]);
  float s = 0.0f;
  float vsl = 0.0f;
#pragma unroll
  for (int o = 0; o < 65; ++o) {
    s += __expf(v[o] - m);
    if (o < 64) vsl = (o == sym) ? v[o] : vsl;
  }
  logZ = m + __logf(s);
  v64 = v[64];
  vs = vsl;
}

__global__ __launch_bounds__(256) void pair_kernel(
    const int* __restrict__ tok_x, const int* __restrict__ tok_y,
    const float* __restrict__ lx_sub, const float* __restrict__ lx_ins,
    const float* __restrict__ ly_sub, const float* __restrict__ ly_ins,
    float* __restrict__ out) {
  const int i = blockIdx.x / SY_;
  const int j = blockIdx.x % SY_;
  const int b = threadIdx.x;
  const size_t CH = (size_t)SX_ * SY_ * B_;
  size_t obase = ((size_t)i * SY_ + j) * B_ + b;

  if (j == SY_ - 1) {  // j_ok false for every b
    out[obase] = BIG_NEG;
    out[CH + obase] = BIG_NEG;
    out[2 * CH + obase] = BIG_NEG;
    out[3 * CH + obase] = BIG_NEG;
    return;
  }

  int tx = tok_x[i * B_ + b];
  int ty = tok_y[j * B_ + b];
  bool valid = (tx >= 0) && (ty >= 0);
  if (!valid) {
    out[obase] = BIG_NEG;
    out[CH + obase] = BIG_NEG;
    out[2 * CH + obase] = BIG_NEG;
    out[3 * CH + obase] = BIG_NEG;
    return;
  }

  int tn = tok_y[(j + 1) * B_ + b];
  bool ins_ok = (tn != 65);
  int sym = (tn >= 0 && tn < 64) ? tn : -1;

  const float* pxs = lx_sub + ((size_t)i * B_ + b) * OP_;
  const float* pys = ly_sub + ((size_t)j * B_ + b) * OP_;
  const float* pxi = lx_ins + ((size_t)i * B_ + b) * OP_;
  const float* pyi = ly_ins + ((size_t)j * B_ + b) * OP_;

  float logZs, v64s, vss;
  head_lse(pxs, pys, sym, logZs, v64s, vss);
  float dlt = v64s - logZs;
  float sub_val = (sym >= 0) ? (vss - logZs) : 0.0f;

  float logZi, v64i, vsi;
  head_lse(pxi, pyi, sym, logZi, v64i, vsi);
  float endv = v64i - logZi;
  float ins_val = (sym >= 0) ? (vsi - logZi) : 0.0f;

  out[obase]          = ins_ok ? ins_val : BIG_NEG;  // ch0: ins
  out[CH + obase]     = ins_ok ? sub_val : BIG_NEG;  // ch1: sub
  out[2 * CH + obase] = endv;                        // ch2: end (valid here)
  out[3 * CH + obase] = dlt;                         // ch3: del
}

// ---------------------------------------------------------------------------
// launch
// ---------------------------------------------------------------------------
extern "C" void kernel_launch(void* const* d_in, const int* in_sizes, int n_in,
                              void* d_out, int out_size, void* d_ws, size_t ws_size,
                              hipStream_t stream) {
  const float* sources = (const float*)d_in[0];
  const float* targets = (const float*)d_in[1];
  const float* Wih_f = (const float*)d_in[2];
  const float* Whh_f = (const float*)d_in[3];
  const float* b_f   = (const float*)d_in[4];
  const float* Wih_r = (const float*)d_in[5];
  const float* Whh_r = (const float*)d_in[6];
  const float* b_r   = (const float*)d_in[7];
  const float* Wih_m = (const float*)d_in[8];
  const float* Whh_m = (const float*)d_in[9];
  const float* b_m   = (const float*)d_in[10];
  const float* W_sub = (const float*)d_in[11];
  const float* b_sub = (const float*)d_in[12];
  const float* W_ins = (const float*)d_in[13];
  const float* b_ins = (const float*)d_in[14];
  float* out = (float*)d_out;

  // workspace layout (all offsets multiples of 256 B)
  char* w = (char*)d_ws;
  constexpr size_t TOK_SZ  = (size_t)SX_ * B_ * 4;              // 34816
  constexpr size_t WHHF_SZ = (size_t)2048 * 512 * 2;            // 2 MiB
  constexpr size_t WHHM_SZ = (size_t)4096 * 1024 * 2;           // 8 MiB
  constexpr size_t WPAD_SZ = (size_t)OP_ * 1024 * 2;            // 160 KiB
  constexpr size_t LX_SZ   = (size_t)SX_ * B_ * OP_ * 4;        // ~2.66 MiB
  constexpr size_t CF_SZ   = (size_t)B_ * 512 * 4;
  constexpr size_t CM_SZ   = (size_t)B_ * 1024 * 4;
  constexpr size_t HF_SZ   = (size_t)35 * B_ * 512 * 2;
  constexpr size_t HM_SZ   = (size_t)35 * B_ * 1024 * 2;

  size_t off = 0;
  int*  tok_x   = (int*)(w + off);  off += TOK_SZ;
  int*  tok_y   = (int*)(w + off);  off += TOK_SZ;
  bf16* Whh_f_b = (bf16*)(w + off); off += WHHF_SZ;
  bf16* Whh_r_b = (bf16*)(w + off); off += WHHF_SZ;
  bf16* Whh_m_b = (bf16*)(w + off); off += WHHM_SZ;
  bf16* Wsub_b  = (bf16*)(w + off); off += WPAD_SZ;
  bf16* Wins_b  = (bf16*)(w + off); off += WPAD_SZ;
  float* lx_sub = (float*)(w + off); off += LX_SZ;
  float* lx_ins = (float*)(w + off); off += LX_SZ;
  float* ly_sub = (float*)(w + off); off += LX_SZ;
  float* ly_ins = (float*)(w + off); off += LX_SZ;
  float* c_f    = (float*)(w + off); off += CF_SZ;
  float* c_r    = (float*)(w + off); off += CF_SZ;
  float* c_m    = (float*)(w + off); off += CM_SZ;
  bf16* fwd_all = (bf16*)(w + off); off += HF_SZ;
  bf16* rev_all = (bf16*)(w + off); off += HF_SZ;
  bf16* y_all   = (bf16*)(w + off); off += HM_SZ;
  (void)ws_size; (void)in_sizes; (void)n_in; (void)out_size;

  // zero-init: c buffers (contiguous) + the three h[0] zero slabs
  hipMemsetAsync(c_f, 0, CF_SZ + CF_SZ + CM_SZ, stream);
  hipMemsetAsync(fwd_all, 0, (size_t)B_ * 512 * 2, stream);
  hipMemsetAsync(rev_all, 0, (size_t)B_ * 512 * 2, stream);
  hipMemsetAsync(y_all,   0, (size_t)B_ * 1024 * 2, stream);

  decode_tokens<<<(2 * SX_ * B_ + 255) / 256, 256, 0, stream>>>(sources, targets, tok_x, tok_y);
  convert_bf16_kernel<<<512, 256, 0, stream>>>(Whh_f, Whh_f_b, 2048 * 512);
  convert_bf16_kernel<<<512, 256, 0, stream>>>(Whh_r, Whh_r_b, 2048 * 512);
  convert_bf16_kernel<<<1024, 256, 0, stream>>>(Whh_m, Whh_m_b, 4096 * 1024);
  pad_head_w<<<(OP_ * 1024 + 255) / 256, 256, 0, stream>>>(W_sub, W_ins, Wsub_b, Wins_b);

  for (int t = 0; t < 34; ++t) {
    lstm_step<<<256, 256, 0, stream>>>(
        t, tok_x, tok_y,
        Wih_f, b_f, Whh_f_b,
        Wih_r, b_r, Whh_r_b,
        Wih_m, b_m, Whh_m_b,
        c_f, c_r, c_m, fwd_all, rev_all, y_all);
  }

  head_kernel<<<272, 256, 0, stream>>>(fwd_all, rev_all, y_all, Wsub_b, Wins_b,
                                       b_sub, b_ins, lx_sub, lx_ins, ly_sub, ly_ins);

  pair_kernel<<<SX_ * SY_, 256, 0, stream>>>(tok_x, tok_y, lx_sub, lx_ins,
                                             ly_sub, ly_ins, out);
}